// Round 2
// baseline (616.250 us; speedup 1.0000x reference)
//
#include <hip/hip_runtime.h>
#include <math.h>

#define BS_TOK 16384   // B*S
#define DIM    2048    // D
#define NEXP   64      // E
#define DHID   1024    // D/2
#define GKS    8       // gate k-split
#define KSL    (DIM / GKS)

typedef __attribute__((ext_vector_type(8))) _Float16 f16x8;
typedef __attribute__((ext_vector_type(4))) float    f32x4;

#define GLOBAL_AS const __attribute__((address_space(1))) void*
#define LDS_AS    __attribute__((address_space(3))) void*

__device__ __forceinline__ float gelu_f(float x) {
  return 0.5f * x * (1.0f + erff(x * 0.70710678118654752440f));
}

// ---------------- LayerNorm -> f16 H ----------------
__global__ __launch_bounds__(256) void ln_kernel(const float* __restrict__ X,
                                                 const float* __restrict__ gamma,
                                                 const float* __restrict__ beta,
                                                 _Float16* __restrict__ H) {
  const int t   = blockIdx.x;
  const int tid = threadIdx.x;
  const float* xr = X + (size_t)t * DIM;
  const float4 a = *(const float4*)(xr + tid * 8);
  const float4 b = *(const float4*)(xr + tid * 8 + 4);
  float xv[8] = {a.x, a.y, a.z, a.w, b.x, b.y, b.z, b.w};
  float s = 0.f, q = 0.f;
#pragma unroll
  for (int j = 0; j < 8; ++j) { s += xv[j]; q += xv[j] * xv[j]; }
#pragma unroll
  for (int off = 32; off > 0; off >>= 1) {
    s += __shfl_xor(s, off);
    q += __shfl_xor(q, off);
  }
  __shared__ float red[8];
  const int w = tid >> 6;
  if ((tid & 63) == 0) { red[w * 2] = s; red[w * 2 + 1] = q; }
  __syncthreads();
  const float ts = red[0] + red[2] + red[4] + red[6];
  const float tq = red[1] + red[3] + red[5] + red[7];
  const float mu  = ts * (1.0f / DIM);
  const float var = tq * (1.0f / DIM) - mu * mu;
  const float rs  = rsqrtf(var + 1e-5f);
  f16x8 h;
#pragma unroll
  for (int j = 0; j < 8; ++j) {
    const int c = tid * 8 + j;
    h[j] = (_Float16)((xv[j] - mu) * rs * gamma[c] + beta[c]);
  }
  *(f16x8*)(H + (size_t)t * DIM + tid * 8) = h;
}

// ---------------- W1 fp32 -> f16 ----------------
__global__ __launch_bounds__(256) void w1cast_kernel(const float* __restrict__ W1,
                                                     _Float16* __restrict__ W1h) {
  const int i = (blockIdx.x * 256 + threadIdx.x) * 8;
  const float4 a = *(const float4*)(W1 + i);
  const float4 b = *(const float4*)(W1 + i + 4);
  f16x8 o;
  o[0] = (_Float16)a.x; o[1] = (_Float16)a.y; o[2] = (_Float16)a.z; o[3] = (_Float16)a.w;
  o[4] = (_Float16)b.x; o[5] = (_Float16)b.y; o[6] = (_Float16)b.z; o[7] = (_Float16)b.w;
  *(f16x8*)(W1h + i) = o;
}

// -------- gate: logits += X . Wg^T  (fp32, 256x64 tile, 8x8 micro, k-split) --------
__global__ __launch_bounds__(256) void gate_kernel(const float* __restrict__ X,
                                                   const float* __restrict__ Wg,
                                                   float* __restrict__ logits) {
  __shared__ float sX[16][264];   // [k][m], padded
  __shared__ float sW[16][68];    // [k][e], padded
  const int tid  = threadIdx.x;
  const int m0   = blockIdx.x * 256;
  const int k0   = blockIdx.y * KSL;
  const int tr   = tid >> 3;      // 0..31, 8 rows each
  const int tc   = tid & 7;       // 0..7, 8 cols each
  const int lrow = tid >> 2;      // 0..63
  const int lkq  = tid & 3;       // k quad
  const float* xb = X  + (size_t)(m0 + lrow) * DIM + lkq * 4;
  const float* wb = Wg + (size_t)lrow * DIM + lkq * 4;
  float acc[8][8] = {};
  float4 rx[4], rw;
#pragma unroll
  for (int r = 0; r < 4; ++r) rx[r] = *(const float4*)(xb + (size_t)r * 64 * DIM + k0);
  rw = *(const float4*)(wb + k0);
  for (int kt = k0; kt < k0 + KSL; kt += 16) {
    __syncthreads();
#pragma unroll
    for (int r = 0; r < 4; ++r) {
      sX[lkq * 4 + 0][r * 64 + lrow] = rx[r].x;
      sX[lkq * 4 + 1][r * 64 + lrow] = rx[r].y;
      sX[lkq * 4 + 2][r * 64 + lrow] = rx[r].z;
      sX[lkq * 4 + 3][r * 64 + lrow] = rx[r].w;
    }
    sW[lkq * 4 + 0][lrow] = rw.x;
    sW[lkq * 4 + 1][lrow] = rw.y;
    sW[lkq * 4 + 2][lrow] = rw.z;
    sW[lkq * 4 + 3][lrow] = rw.w;
    int ktn = kt + 16;
    if (ktn >= k0 + KSL) ktn = k0;   // harmless reload on last iter
#pragma unroll
    for (int r = 0; r < 4; ++r) rx[r] = *(const float4*)(xb + (size_t)r * 64 * DIM + ktn);
    rw = *(const float4*)(wb + ktn);
    __syncthreads();
#pragma unroll
    for (int k = 0; k < 16; ++k) {
      float av[8], bv[8];
      *(float4*)(av)     = *(const float4*)&sX[k][tr * 8];
      *(float4*)(av + 4) = *(const float4*)&sX[k][tr * 8 + 4];
      *(float4*)(bv)     = *(const float4*)&sW[k][tc * 8];
      *(float4*)(bv + 4) = *(const float4*)&sW[k][tc * 8 + 4];
#pragma unroll
      for (int i = 0; i < 8; ++i)
#pragma unroll
        for (int j = 0; j < 8; ++j) acc[i][j] += av[i] * bv[j];
    }
  }
#pragma unroll
  for (int i = 0; i < 8; ++i) {
    float* orow = logits + (size_t)(m0 + tr * 8 + i) * NEXP + tc * 8;
#pragma unroll
    for (int j = 0; j < 8; ++j) atomicAdd(orow + j, acc[i][j]);
  }
}

// ------- predictor GEMM: H1 = gelu(H . W1^T); z[t] += sum_n H1*W2 (fused) -------
__global__ __launch_bounds__(256) void g2_kernel(const _Float16* __restrict__ H,
                                                 const _Float16* __restrict__ W1h,
                                                 const float* __restrict__ W2,
                                                 float* __restrict__ diffz) {
  __shared__ __align__(16) _Float16 sA[128 * 32];
  __shared__ __align__(16) _Float16 sB[128 * 32];
  const int tid  = threadIdx.x;
  const int n0   = blockIdx.x * 128;   // n fast -> W1 tiles stay L2-hot
  const int m0   = blockIdx.y * 128;
  const int w    = tid >> 6, lane = tid & 63;
  const int wr   = w >> 1,  wc   = w & 1;
  const int col  = lane & 15, quad = lane >> 4;
  const int row0 = tid >> 2,  kp = tid & 3;
  const int row1 = row0 + 64;
  const _Float16* gA0 = H   + (size_t)(m0 + row0) * DIM + kp * 8;
  const _Float16* gA1 = H   + (size_t)(m0 + row1) * DIM + kp * 8;
  const _Float16* gB0 = W1h + (size_t)(n0 + row0) * DIM + kp * 8;
  const _Float16* gB1 = W1h + (size_t)(n0 + row1) * DIM + kp * 8;
  f32x4 acc[4][4] = {};
  for (int kt = 0; kt < DIM; kt += 32) {
    __syncthreads();
    __builtin_amdgcn_global_load_lds((GLOBAL_AS)(gA0 + kt), (LDS_AS)(sA + tid * 8), 16, 0, 0);
    __builtin_amdgcn_global_load_lds((GLOBAL_AS)(gA1 + kt), (LDS_AS)(sA + (256 + tid) * 8), 16, 0, 0);
    __builtin_amdgcn_global_load_lds((GLOBAL_AS)(gB0 + kt), (LDS_AS)(sB + tid * 8), 16, 0, 0);
    __builtin_amdgcn_global_load_lds((GLOBAL_AS)(gB1 + kt), (LDS_AS)(sB + (256 + tid) * 8), 16, 0, 0);
    __syncthreads();
    f16x8 af[4], bf[4];
#pragma unroll
    for (int mi = 0; mi < 4; ++mi)
      af[mi] = *(const f16x8*)(sA + (wr * 64 + mi * 16 + col) * 32 + quad * 8);
#pragma unroll
    for (int ni = 0; ni < 4; ++ni)
      bf[ni] = *(const f16x8*)(sB + (wc * 64 + ni * 16 + col) * 32 + quad * 8);
#pragma unroll
    for (int mi = 0; mi < 4; ++mi)
#pragma unroll
      for (int ni = 0; ni < 4; ++ni)
        acc[mi][ni] = __builtin_amdgcn_mfma_f32_16x16x32_f16(af[mi], bf[ni], acc[mi][ni], 0, 0, 0);
  }
  // epilogue: gelu -> * W2 -> reduce over the 128 n-cols this block owns
  float w2v[4];
#pragma unroll
  for (int ni = 0; ni < 4; ++ni) w2v[ni] = W2[n0 + wc * 64 + ni * 16 + col];
#pragma unroll
  for (int mi = 0; mi < 4; ++mi) {
#pragma unroll
    for (int reg = 0; reg < 4; ++reg) {
      float v = 0.f;
#pragma unroll
      for (int ni = 0; ni < 4; ++ni) v += gelu_f(acc[mi][ni][reg]) * w2v[ni];
      v += __shfl_xor(v, 1);
      v += __shfl_xor(v, 2);
      v += __shfl_xor(v, 4);
      v += __shfl_xor(v, 8);
      if (col == 0)
        atomicAdd(diffz + m0 + wr * 64 + mi * 16 + quad * 4 + reg, v);
    }
  }
}

// ---------------- per-token finalize: one wave per token, 32 tokens/block ----------------
__global__ __launch_bounds__(256) void finalize_kernel(const float* __restrict__ logits,
                                                       const float* __restrict__ diffz,
                                                       float* __restrict__ out_idx,
                                                       float* __restrict__ out_scores,
                                                       float* __restrict__ out_probs,
                                                       float* __restrict__ imp_acc,
                                                       float* __restrict__ load_acc) {
  const int tid  = threadIdx.x;
  const int w    = tid >> 6, lane = tid & 63;
  float acc_imp = 0.f, acc_load = 0.f;
  for (int it = 0; it < 8; ++it) {
    const int t    = blockIdx.x * 32 + it * 4 + w;
    const float L  = logits[(size_t)t * NEXP + lane];
    const float z  = diffz[t];
    const float d  = 1.0f / (1.0f + expf(-z));
    const float l  = L / (1.0f + d);          // TEMP == 1
    // softmax
    float m = l;
#pragma unroll
    for (int off = 32; off > 0; off >>= 1) m = fmaxf(m, __shfl_xor(m, off));
    float p = expf(l - m);
    float s = p;
#pragma unroll
    for (int off = 32; off > 0; off >>= 1) s += __shfl_xor(s, off);
    p /= s;
    // top-1 (jax tie-break: lower index wins)
    float v = l; int bi = lane;
#pragma unroll
    for (int off = 32; off > 0; off >>= 1) {
      const float ov = __shfl_xor(v, off);
      const int   oi = __shfl_xor(bi, off);
      if (ov > v || (ov == v && oi < bi)) { v = ov; bi = oi; }
    }
    const int i1 = bi;
    // top-2
    float v2 = (lane == i1) ? -INFINITY : l;
    int bi2 = lane;
#pragma unroll
    for (int off = 32; off > 0; off >>= 1) {
      const float ov = __shfl_xor(v2, off);
      const int   oi = __shfl_xor(bi2, off);
      if (ov > v2 || (ov == v2 && oi < bi2)) { v2 = ov; bi2 = oi; }
    }
    const int i2 = bi2;
    const float p1 = __shfl(p, i1);
    const float p2 = __shfl(p, i2);
    const float s1 = (1.0f - p1) + p1;        // straight-through, fp32-faithful
    const float s2 = (1.0f - p2) + p2;
    const float den = fmaxf(s1 + s2, 1e-9f);
    if (lane == 0) {
      out_idx[t * 2]        = (float)i1;
      out_idx[t * 2 + 1]    = (float)i2;
      out_scores[t * 2]     = s1 / den;
      out_scores[t * 2 + 1] = s2 / den;
    }
    out_probs[(size_t)t * NEXP + lane] = p;
    acc_imp  += p;
    acc_load += (lane == i1 || lane == i2) ? 1.0f : 0.0f;
  }
  __shared__ float s_imp[256];
  __shared__ float s_hard[256];
  s_imp[tid]  = acc_imp;
  s_hard[tid] = acc_load;
  __syncthreads();
  if (tid < 64) {
    const float si = s_imp[tid] + s_imp[64 + tid] + s_imp[128 + tid] + s_imp[192 + tid];
    const float sl = s_hard[tid] + s_hard[64 + tid] + s_hard[128 + tid] + s_hard[192 + tid];
    atomicAdd(imp_acc + tid, si);
    atomicAdd(load_acc + tid, sl);
  }
}

// ---------------- importance/load scale ----------------
__global__ void scale_kernel(const float* __restrict__ acc,
                             float* __restrict__ out_imp,
                             float* __restrict__ out_load) {
  const int tid = threadIdx.x;
  const float inv = 1.0f / 16384.0f;
  if (tid < 64)       out_imp[tid]        = acc[tid] * inv;
  else if (tid < 128) out_load[tid - 64]  = acc[tid] * inv;
}

extern "C" void kernel_launch(void* const* d_in, const int* in_sizes, int n_in,
                              void* d_out, int out_size, void* d_ws, size_t ws_size,
                              hipStream_t stream) {
  (void)in_sizes; (void)n_in; (void)out_size; (void)ws_size;
  const float* X     = (const float*)d_in[0];
  const float* Wg    = (const float*)d_in[1];
  const float* gamma = (const float*)d_in[2];
  const float* beta  = (const float*)d_in[3];
  const float* W1    = (const float*)d_in[4];
  const float* W2    = (const float*)d_in[5];
  float* out = (float*)d_out;

  char* ws = (char*)d_ws;
  _Float16* H      = (_Float16*)(ws);                    // 64 MB
  _Float16* W1h    = (_Float16*)(ws + 67108864ull);      // 4 MB
  float*    logits = (float*)  (ws + 71303168ull);       // 4 MB (atomic target)
  float*    diffz  = (float*)  (ws + 75497472ull);       // 64 KB
  float*    accs   = (float*)  (ws + 75563008ull);       // 512 B (imp[64], load[64])

  // out layout (all float32): idx[32768] | scores[32768] | probs[1048576] | imp[64] | load[64]
  float* out_idx    = out;
  float* out_scores = out + 32768;
  float* out_probs  = out + 65536;
  float* out_imp    = out + 1114112;
  float* out_load   = out + 1114176;

  // zero logits + diffz + accs in one contiguous memset
  hipMemsetAsync(logits, 0, 4194304ull + 65536ull + 512ull, stream);
  ln_kernel<<<BS_TOK, 256, 0, stream>>>(X, gamma, beta, H);
  w1cast_kernel<<<(DHID * DIM) / (256 * 8), 256, 0, stream>>>(W1, W1h);
  gate_kernel<<<dim3(BS_TOK / 256, GKS), 256, 0, stream>>>(X, Wg, logits);
  g2_kernel<<<dim3(DHID / 128, BS_TOK / 128), 256, 0, stream>>>(H, W1h, W2, diffz);
  finalize_kernel<<<BS_TOK / 32, 256, 0, stream>>>(logits, diffz, out_idx, out_scores,
                                                   out_probs, accs, accs + 64);
  scale_kernel<<<1, 128, 0, stream>>>(accs, out_imp, out_load);
}

// Round 3
// 418.458 us; speedup vs baseline: 1.4727x; 1.4727x over previous
//
#include <hip/hip_runtime.h>
#include <math.h>

#define BS_TOK 16384   // B*S
#define DIM    2048    // D
#define NEXP   64      // E
#define DHID   1024    // D/2
#define GKS    4       // gate k-split
#define KSL    (DIM / GKS)

typedef __attribute__((ext_vector_type(8))) _Float16 f16x8;
typedef __attribute__((ext_vector_type(4))) float    f32x4;

#define GLOBAL_AS const __attribute__((address_space(1))) void*
#define LDS_AS    __attribute__((address_space(3))) void*

__device__ __forceinline__ float gelu_f(float x) {
  return 0.5f * x * (1.0f + erff(x * 0.70710678118654752440f));
}

// ---------------- LayerNorm -> f16 H ----------------
__global__ __launch_bounds__(256) void ln_kernel(const float* __restrict__ X,
                                                 const float* __restrict__ gamma,
                                                 const float* __restrict__ beta,
                                                 _Float16* __restrict__ H) {
  const int t   = blockIdx.x;
  const int tid = threadIdx.x;
  const float* xr = X + (size_t)t * DIM;
  const float4 a = *(const float4*)(xr + tid * 8);
  const float4 b = *(const float4*)(xr + tid * 8 + 4);
  float xv[8] = {a.x, a.y, a.z, a.w, b.x, b.y, b.z, b.w};
  float s = 0.f, q = 0.f;
#pragma unroll
  for (int j = 0; j < 8; ++j) { s += xv[j]; q += xv[j] * xv[j]; }
#pragma unroll
  for (int off = 32; off > 0; off >>= 1) {
    s += __shfl_xor(s, off);
    q += __shfl_xor(q, off);
  }
  __shared__ float red[8];
  const int w = tid >> 6;
  if ((tid & 63) == 0) { red[w * 2] = s; red[w * 2 + 1] = q; }
  __syncthreads();
  const float ts = red[0] + red[2] + red[4] + red[6];
  const float tq = red[1] + red[3] + red[5] + red[7];
  const float mu  = ts * (1.0f / DIM);
  const float var = tq * (1.0f / DIM) - mu * mu;
  const float rs  = rsqrtf(var + 1e-5f);
  f16x8 h;
#pragma unroll
  for (int j = 0; j < 8; ++j) {
    const int c = tid * 8 + j;
    h[j] = (_Float16)((xv[j] - mu) * rs * gamma[c] + beta[c]);
  }
  *(f16x8*)(H + (size_t)t * DIM + tid * 8) = h;
}

// ---------------- W1 fp32 -> f16 ----------------
__global__ __launch_bounds__(256) void w1cast_kernel(const float* __restrict__ W1,
                                                     _Float16* __restrict__ W1h) {
  const int i = (blockIdx.x * 256 + threadIdx.x) * 8;
  const float4 a = *(const float4*)(W1 + i);
  const float4 b = *(const float4*)(W1 + i + 4);
  f16x8 o;
  o[0] = (_Float16)a.x; o[1] = (_Float16)a.y; o[2] = (_Float16)a.z; o[3] = (_Float16)a.w;
  o[4] = (_Float16)b.x; o[5] = (_Float16)b.y; o[6] = (_Float16)b.z; o[7] = (_Float16)b.w;
  *(f16x8*)(W1h + i) = o;
}

// -------- gate partials: logitsP[ks] = X[:, ks] . Wg[:, ks]^T ----------
// 64x64 tile, 4x4 micro (16 acc VGPRs -> no spill), k-split 4, plain stores.
__global__ __launch_bounds__(256) void gate_kernel(const float* __restrict__ X,
                                                   const float* __restrict__ Wg,
                                                   float* __restrict__ logitsP) {
  __shared__ float sX[16][68];   // [k][m], padded
  __shared__ float sW[16][68];   // [k][e], padded
  const int tid  = threadIdx.x;
  const int m0   = blockIdx.x * 64;
  const int k0   = blockIdx.y * KSL;
  const int srow = tid >> 2;      // 0..63 staging row
  const int skq  = tid & 3;       // k-quad
  const int ty   = tid >> 4;      // 0..15 token group (4 tokens)
  const int tx   = tid & 15;      // 0..15 expert group (4 experts)
  const float* xb = X  + (size_t)(m0 + srow) * DIM + k0 + skq * 4;
  const float* wb = Wg + (size_t)srow * DIM + k0 + skq * 4;
  float acc[4][4] = {};
  float4 rx = *(const float4*)xb;
  float4 rw = *(const float4*)wb;
  for (int kt = 0; kt < KSL; kt += 16) {
    __syncthreads();
    sX[skq * 4 + 0][srow] = rx.x;
    sX[skq * 4 + 1][srow] = rx.y;
    sX[skq * 4 + 2][srow] = rx.z;
    sX[skq * 4 + 3][srow] = rx.w;
    sW[skq * 4 + 0][srow] = rw.x;
    sW[skq * 4 + 1][srow] = rw.y;
    sW[skq * 4 + 2][srow] = rw.z;
    sW[skq * 4 + 3][srow] = rw.w;
    const int ktn = (kt + 16 < KSL) ? kt + 16 : 0;   // harmless reload on last iter
    rx = *(const float4*)(xb + ktn);
    rw = *(const float4*)(wb + ktn);
    __syncthreads();
#pragma unroll
    for (int k = 0; k < 16; ++k) {
      const float4 a4 = *(const float4*)&sX[k][ty * 4];
      const float4 b4 = *(const float4*)&sW[k][tx * 4];
      const float av[4] = {a4.x, a4.y, a4.z, a4.w};
      const float bv[4] = {b4.x, b4.y, b4.z, b4.w};
#pragma unroll
      for (int i = 0; i < 4; ++i)
#pragma unroll
        for (int j = 0; j < 4; ++j) acc[i][j] += av[i] * bv[j];
    }
  }
  float* op = logitsP + (size_t)blockIdx.y * (BS_TOK * NEXP)
            + (size_t)(m0 + ty * 4) * NEXP + tx * 4;
#pragma unroll
  for (int i = 0; i < 4; ++i) {
    float4 o;
    o.x = acc[i][0]; o.y = acc[i][1]; o.z = acc[i][2]; o.w = acc[i][3];
    *(float4*)(op + (size_t)i * NEXP) = o;
  }
}

// ------- predictor GEMM: H1 = gelu(H . W1^T); z[t] += sum_n H1*W2 (fused) -------
__global__ __launch_bounds__(256) void g2_kernel(const _Float16* __restrict__ H,
                                                 const _Float16* __restrict__ W1h,
                                                 const float* __restrict__ W2,
                                                 float* __restrict__ diffz) {
  __shared__ __align__(16) _Float16 sA[128 * 32];
  __shared__ __align__(16) _Float16 sB[128 * 32];
  const int tid  = threadIdx.x;
  const int n0   = blockIdx.x * 128;   // n fast -> W1 tiles stay L2-hot
  const int m0   = blockIdx.y * 128;
  const int w    = tid >> 6, lane = tid & 63;
  const int wr   = w >> 1,  wc   = w & 1;
  const int col  = lane & 15, quad = lane >> 4;
  const int row0 = tid >> 2,  kp = tid & 3;
  const int row1 = row0 + 64;
  const _Float16* gA0 = H   + (size_t)(m0 + row0) * DIM + kp * 8;
  const _Float16* gA1 = H   + (size_t)(m0 + row1) * DIM + kp * 8;
  const _Float16* gB0 = W1h + (size_t)(n0 + row0) * DIM + kp * 8;
  const _Float16* gB1 = W1h + (size_t)(n0 + row1) * DIM + kp * 8;
  f32x4 acc[4][4] = {};
  for (int kt = 0; kt < DIM; kt += 32) {
    __syncthreads();
    __builtin_amdgcn_global_load_lds((GLOBAL_AS)(gA0 + kt), (LDS_AS)(sA + tid * 8), 16, 0, 0);
    __builtin_amdgcn_global_load_lds((GLOBAL_AS)(gA1 + kt), (LDS_AS)(sA + (256 + tid) * 8), 16, 0, 0);
    __builtin_amdgcn_global_load_lds((GLOBAL_AS)(gB0 + kt), (LDS_AS)(sB + tid * 8), 16, 0, 0);
    __builtin_amdgcn_global_load_lds((GLOBAL_AS)(gB1 + kt), (LDS_AS)(sB + (256 + tid) * 8), 16, 0, 0);
    __syncthreads();
    f16x8 af[4], bf[4];
#pragma unroll
    for (int mi = 0; mi < 4; ++mi)
      af[mi] = *(const f16x8*)(sA + (wr * 64 + mi * 16 + col) * 32 + quad * 8);
#pragma unroll
    for (int ni = 0; ni < 4; ++ni)
      bf[ni] = *(const f16x8*)(sB + (wc * 64 + ni * 16 + col) * 32 + quad * 8);
#pragma unroll
    for (int mi = 0; mi < 4; ++mi)
#pragma unroll
      for (int ni = 0; ni < 4; ++ni)
        acc[mi][ni] = __builtin_amdgcn_mfma_f32_16x16x32_f16(af[mi], bf[ni], acc[mi][ni], 0, 0, 0);
  }
  // epilogue: gelu -> * W2 -> reduce over the 128 n-cols this block owns
  float w2v[4];
#pragma unroll
  for (int ni = 0; ni < 4; ++ni) w2v[ni] = W2[n0 + wc * 64 + ni * 16 + col];
#pragma unroll
  for (int mi = 0; mi < 4; ++mi) {
#pragma unroll
    for (int reg = 0; reg < 4; ++reg) {
      float v = 0.f;
#pragma unroll
      for (int ni = 0; ni < 4; ++ni) v += gelu_f(acc[mi][ni][reg]) * w2v[ni];
      v += __shfl_xor(v, 1);
      v += __shfl_xor(v, 2);
      v += __shfl_xor(v, 4);
      v += __shfl_xor(v, 8);
      if (col == 0)
        atomicAdd(diffz + m0 + wr * 64 + mi * 16 + quad * 4 + reg, v);
    }
  }
}

// ---------------- per-token finalize: one wave per token, 32 tokens/block ----------------
__global__ __launch_bounds__(256) void finalize_kernel(const float* __restrict__ logitsP,
                                                       const float* __restrict__ diffz,
                                                       float* __restrict__ out_idx,
                                                       float* __restrict__ out_scores,
                                                       float* __restrict__ out_probs,
                                                       float* __restrict__ imp_acc,
                                                       float* __restrict__ load_acc) {
  const int tid  = threadIdx.x;
  const int w    = tid >> 6, lane = tid & 63;
  const size_t PS = (size_t)BS_TOK * NEXP;
  float acc_imp = 0.f, acc_load = 0.f;
  for (int it = 0; it < 8; ++it) {
    const int t    = blockIdx.x * 32 + it * 4 + w;
    const float* lp = logitsP + (size_t)t * NEXP + lane;
    const float L  = ((lp[0] + lp[PS]) + lp[2 * PS]) + lp[3 * PS];
    const float z  = diffz[t];
    const float d  = 1.0f / (1.0f + expf(-z));
    const float l  = L / (1.0f + d);          // TEMP == 1
    // softmax
    float m = l;
#pragma unroll
    for (int off = 32; off > 0; off >>= 1) m = fmaxf(m, __shfl_xor(m, off));
    float p = expf(l - m);
    float s = p;
#pragma unroll
    for (int off = 32; off > 0; off >>= 1) s += __shfl_xor(s, off);
    p /= s;
    // top-1 (jax tie-break: lower index wins)
    float v = l; int bi = lane;
#pragma unroll
    for (int off = 32; off > 0; off >>= 1) {
      const float ov = __shfl_xor(v, off);
      const int   oi = __shfl_xor(bi, off);
      if (ov > v || (ov == v && oi < bi)) { v = ov; bi = oi; }
    }
    const int i1 = bi;
    // top-2
    float v2 = (lane == i1) ? -INFINITY : l;
    int bi2 = lane;
#pragma unroll
    for (int off = 32; off > 0; off >>= 1) {
      const float ov = __shfl_xor(v2, off);
      const int   oi = __shfl_xor(bi2, off);
      if (ov > v2 || (ov == v2 && oi < bi2)) { v2 = ov; bi2 = oi; }
    }
    const int i2 = bi2;
    const float p1 = __shfl(p, i1);
    const float p2 = __shfl(p, i2);
    const float s1 = (1.0f - p1) + p1;        // straight-through, fp32-faithful
    const float s2 = (1.0f - p2) + p2;
    const float den = fmaxf(s1 + s2, 1e-9f);
    if (lane == 0) {
      out_idx[t * 2]        = (float)i1;
      out_idx[t * 2 + 1]    = (float)i2;
      out_scores[t * 2]     = s1 / den;
      out_scores[t * 2 + 1] = s2 / den;
    }
    out_probs[(size_t)t * NEXP + lane] = p;
    acc_imp  += p;
    acc_load += (lane == i1 || lane == i2) ? 1.0f : 0.0f;
  }
  __shared__ float s_imp[256];
  __shared__ float s_hard[256];
  s_imp[tid]  = acc_imp;
  s_hard[tid] = acc_load;
  __syncthreads();
  if (tid < 64) {
    const float si = s_imp[tid] + s_imp[64 + tid] + s_imp[128 + tid] + s_imp[192 + tid];
    const float sl = s_hard[tid] + s_hard[64 + tid] + s_hard[128 + tid] + s_hard[192 + tid];
    atomicAdd(imp_acc + tid, si);
    atomicAdd(load_acc + tid, sl);
  }
}

// ---------------- importance/load scale ----------------
__global__ void scale_kernel(const float* __restrict__ acc,
                             float* __restrict__ out_imp,
                             float* __restrict__ out_load) {
  const int tid = threadIdx.x;
  const float inv = 1.0f / 16384.0f;
  if (tid < 64)       out_imp[tid]        = acc[tid] * inv;
  else if (tid < 128) out_load[tid - 64]  = acc[tid] * inv;
}

extern "C" void kernel_launch(void* const* d_in, const int* in_sizes, int n_in,
                              void* d_out, int out_size, void* d_ws, size_t ws_size,
                              hipStream_t stream) {
  (void)in_sizes; (void)n_in; (void)out_size; (void)ws_size;
  const float* X     = (const float*)d_in[0];
  const float* Wg    = (const float*)d_in[1];
  const float* gamma = (const float*)d_in[2];
  const float* beta  = (const float*)d_in[3];
  const float* W1    = (const float*)d_in[4];
  const float* W2    = (const float*)d_in[5];
  float* out = (float*)d_out;

  char* ws = (char*)d_ws;
  _Float16* H       = (_Float16*)(ws);                    // 64 MB
  _Float16* W1h     = (_Float16*)(ws + 67108864ull);      // 4 MB
  float*    logitsP = (float*)  (ws + 71303168ull);       // 16 MB (4 k-split partials)
  float*    diffz   = (float*)  (ws + 88080384ull);       // 64 KB
  float*    accs    = (float*)  (ws + 88145920ull);       // 512 B (imp[64], load[64])

  // out layout (all float32): idx[32768] | scores[32768] | probs[1048576] | imp[64] | load[64]
  float* out_idx    = out;
  float* out_scores = out + 32768;
  float* out_probs  = out + 65536;
  float* out_imp    = out + 1114112;
  float* out_load   = out + 1114176;

  hipMemsetAsync(diffz, 0, 65536ull + 512ull, stream);
  ln_kernel<<<BS_TOK, 256, 0, stream>>>(X, gamma, beta, H);
  w1cast_kernel<<<(DHID * DIM) / (256 * 8), 256, 0, stream>>>(W1, W1h);
  gate_kernel<<<dim3(BS_TOK / 64, GKS), 256, 0, stream>>>(X, Wg, logitsP);
  g2_kernel<<<dim3(DHID / 128, BS_TOK / 128), 256, 0, stream>>>(H, W1h, W2, diffz);
  finalize_kernel<<<BS_TOK / 32, 256, 0, stream>>>(logitsP, diffz, out_idx, out_scores,
                                                   out_probs, accs, accs + 64);
  scale_kernel<<<1, 128, 0, stream>>>(accs, out_imp, out_load);
}

// Round 4
// 409.704 us; speedup vs baseline: 1.5041x; 1.0214x over previous
//
#include <hip/hip_runtime.h>
#include <math.h>

#define BS_TOK 16384   // B*S
#define DIM    2048    // D
#define NEXP   64      // E
#define DHID   1024    // D/2
#define GKS    4       // gate k-split
#define KSL    (DIM / GKS)

typedef __attribute__((ext_vector_type(8))) _Float16 f16x8;
typedef __attribute__((ext_vector_type(4))) float    f32x4;

#define GLOBAL_AS const __attribute__((address_space(1))) void*
#define LDS_AS    __attribute__((address_space(3))) void*

__device__ __forceinline__ float gelu_f(float x) {
  return 0.5f * x * (1.0f + erff(x * 0.70710678118654752440f));
}

// ---------------- LayerNorm -> f16 H : one wave per token, no LDS ----------------
__global__ __launch_bounds__(256) void ln_kernel(const float* __restrict__ X,
                                                 const float* __restrict__ gamma,
                                                 const float* __restrict__ beta,
                                                 _Float16* __restrict__ H) {
  const int tid  = threadIdx.x;
  const int w    = tid >> 6, lane = tid & 63;
  const int t    = blockIdx.x * 4 + w;
  const float* xr = X + (size_t)t * DIM;
  float4 xv[8];
#pragma unroll
  for (int j = 0; j < 4; ++j) {
    const int c0 = (j * 64 + lane) * 8;
    xv[j * 2]     = *(const float4*)(xr + c0);
    xv[j * 2 + 1] = *(const float4*)(xr + c0 + 4);
  }
  float s = 0.f, q = 0.f;
#pragma unroll
  for (int j = 0; j < 8; ++j) {
    s += (xv[j].x + xv[j].y) + (xv[j].z + xv[j].w);
    q += (xv[j].x * xv[j].x + xv[j].y * xv[j].y) + (xv[j].z * xv[j].z + xv[j].w * xv[j].w);
  }
#pragma unroll
  for (int off = 32; off > 0; off >>= 1) {
    s += __shfl_xor(s, off);
    q += __shfl_xor(q, off);
  }
  const float mu  = s * (1.0f / DIM);
  const float var = q * (1.0f / DIM) - mu * mu;
  const float rs  = rsqrtf(var + 1e-5f);
#pragma unroll
  for (int j = 0; j < 4; ++j) {
    const int c0 = (j * 64 + lane) * 8;
    const float4 g0 = *(const float4*)(gamma + c0);
    const float4 g1 = *(const float4*)(gamma + c0 + 4);
    const float4 b0 = *(const float4*)(beta + c0);
    const float4 b1 = *(const float4*)(beta + c0 + 4);
    const float4 a = xv[j * 2], b = xv[j * 2 + 1];
    f16x8 h;
    h[0] = (_Float16)((a.x - mu) * rs * g0.x + b0.x);
    h[1] = (_Float16)((a.y - mu) * rs * g0.y + b0.y);
    h[2] = (_Float16)((a.z - mu) * rs * g0.z + b0.z);
    h[3] = (_Float16)((a.w - mu) * rs * g0.w + b0.w);
    h[4] = (_Float16)((b.x - mu) * rs * g1.x + b1.x);
    h[5] = (_Float16)((b.y - mu) * rs * g1.y + b1.y);
    h[6] = (_Float16)((b.z - mu) * rs * g1.z + b1.z);
    h[7] = (_Float16)((b.w - mu) * rs * g1.w + b1.w);
    *(f16x8*)(H + (size_t)t * DIM + c0) = h;
  }
}

// ---------------- W1 fp32 -> f16 ----------------
__global__ __launch_bounds__(256) void w1cast_kernel(const float* __restrict__ W1,
                                                     _Float16* __restrict__ W1h) {
  const int i = (blockIdx.x * 256 + threadIdx.x) * 8;
  const float4 a = *(const float4*)(W1 + i);
  const float4 b = *(const float4*)(W1 + i + 4);
  f16x8 o;
  o[0] = (_Float16)a.x; o[1] = (_Float16)a.y; o[2] = (_Float16)a.z; o[3] = (_Float16)a.w;
  o[4] = (_Float16)b.x; o[5] = (_Float16)b.y; o[6] = (_Float16)b.z; o[7] = (_Float16)b.w;
  *(f16x8*)(W1h + i) = o;
}

// -------- gate partials: logitsP[ks] = X[:, ks] . Wg[:, ks]^T ----------
// 64x64 tile, 4x4 micro (16 acc VGPRs -> no spill), k-split 4, plain stores.
__global__ __launch_bounds__(256) void gate_kernel(const float* __restrict__ X,
                                                   const float* __restrict__ Wg,
                                                   float* __restrict__ logitsP) {
  __shared__ float sX[16][68];   // [k][m], padded
  __shared__ float sW[16][68];   // [k][e], padded
  const int tid  = threadIdx.x;
  const int m0   = blockIdx.x * 64;
  const int k0   = blockIdx.y * KSL;
  const int srow = tid >> 2;      // 0..63 staging row
  const int skq  = tid & 3;       // k-quad
  const int ty   = tid >> 4;      // 0..15 token group (4 tokens)
  const int tx   = tid & 15;      // 0..15 expert group (4 experts)
  const float* xb = X  + (size_t)(m0 + srow) * DIM + k0 + skq * 4;
  const float* wb = Wg + (size_t)srow * DIM + k0 + skq * 4;
  float acc[4][4] = {};
  float4 rx = *(const float4*)xb;
  float4 rw = *(const float4*)wb;
  for (int kt = 0; kt < KSL; kt += 16) {
    __syncthreads();
    sX[skq * 4 + 0][srow] = rx.x;
    sX[skq * 4 + 1][srow] = rx.y;
    sX[skq * 4 + 2][srow] = rx.z;
    sX[skq * 4 + 3][srow] = rx.w;
    sW[skq * 4 + 0][srow] = rw.x;
    sW[skq * 4 + 1][srow] = rw.y;
    sW[skq * 4 + 2][srow] = rw.z;
    sW[skq * 4 + 3][srow] = rw.w;
    const int ktn = (kt + 16 < KSL) ? kt + 16 : 0;   // harmless reload on last iter
    rx = *(const float4*)(xb + ktn);
    rw = *(const float4*)(wb + ktn);
    __syncthreads();
#pragma unroll
    for (int k = 0; k < 16; ++k) {
      const float4 a4 = *(const float4*)&sX[k][ty * 4];
      const float4 b4 = *(const float4*)&sW[k][tx * 4];
      const float av[4] = {a4.x, a4.y, a4.z, a4.w};
      const float bv[4] = {b4.x, b4.y, b4.z, b4.w};
#pragma unroll
      for (int i = 0; i < 4; ++i)
#pragma unroll
        for (int j = 0; j < 4; ++j) acc[i][j] += av[i] * bv[j];
    }
  }
  float* op = logitsP + (size_t)blockIdx.y * (BS_TOK * NEXP)
            + (size_t)(m0 + ty * 4) * NEXP + tx * 4;
#pragma unroll
  for (int i = 0; i < 4; ++i) {
    float4 o;
    o.x = acc[i][0]; o.y = acc[i][1]; o.z = acc[i][2]; o.w = acc[i][3];
    *(float4*)(op + (size_t)i * NEXP) = o;
  }
}

// ------- predictor GEMM: H1 = gelu(H . W1^T); z[t] += sum_n H1*W2 (fused) -------
// XCD-swizzled 1-D grid: c = bid&7 (~XCD), XCD c owns m-tiles [16c,16c+16), n fastest
// so same-m blocks share one XCD's L2 for the H tile.
__global__ __launch_bounds__(256) void g2_kernel(const _Float16* __restrict__ H,
                                                 const _Float16* __restrict__ W1h,
                                                 const float* __restrict__ W2,
                                                 float* __restrict__ diffz) {
  __shared__ __align__(16) _Float16 sA[128 * 32];
  __shared__ __align__(16) _Float16 sB[128 * 32];
  const int bid = blockIdx.x;
  const int c   = bid & 7;
  const int j   = bid >> 3;
  const int m0  = (c * 16 + (j >> 3)) * 128;
  const int n0  = (j & 7) * 128;
  const int tid  = threadIdx.x;
  const int w    = tid >> 6, lane = tid & 63;
  const int wr   = w >> 1,  wc   = w & 1;
  const int col  = lane & 15, quad = lane >> 4;
  const int row0 = tid >> 2,  kp = tid & 3;
  const int row1 = row0 + 64;
  const _Float16* gA0 = H   + (size_t)(m0 + row0) * DIM + kp * 8;
  const _Float16* gA1 = H   + (size_t)(m0 + row1) * DIM + kp * 8;
  const _Float16* gB0 = W1h + (size_t)(n0 + row0) * DIM + kp * 8;
  const _Float16* gB1 = W1h + (size_t)(n0 + row1) * DIM + kp * 8;
  f32x4 acc[4][4] = {};
  for (int kt = 0; kt < DIM; kt += 32) {
    __syncthreads();
    __builtin_amdgcn_global_load_lds((GLOBAL_AS)(gA0 + kt), (LDS_AS)(sA + tid * 8), 16, 0, 0);
    __builtin_amdgcn_global_load_lds((GLOBAL_AS)(gA1 + kt), (LDS_AS)(sA + (256 + tid) * 8), 16, 0, 0);
    __builtin_amdgcn_global_load_lds((GLOBAL_AS)(gB0 + kt), (LDS_AS)(sB + tid * 8), 16, 0, 0);
    __builtin_amdgcn_global_load_lds((GLOBAL_AS)(gB1 + kt), (LDS_AS)(sB + (256 + tid) * 8), 16, 0, 0);
    __syncthreads();
    f16x8 af[4], bf[4];
#pragma unroll
    for (int mi = 0; mi < 4; ++mi)
      af[mi] = *(const f16x8*)(sA + (wr * 64 + mi * 16 + col) * 32 + quad * 8);
#pragma unroll
    for (int ni = 0; ni < 4; ++ni)
      bf[ni] = *(const f16x8*)(sB + (wc * 64 + ni * 16 + col) * 32 + quad * 8);
#pragma unroll
    for (int mi = 0; mi < 4; ++mi)
#pragma unroll
      for (int ni = 0; ni < 4; ++ni)
        acc[mi][ni] = __builtin_amdgcn_mfma_f32_16x16x32_f16(af[mi], bf[ni], acc[mi][ni], 0, 0, 0);
  }
  // epilogue: gelu -> * W2 -> reduce over the 128 n-cols this block owns
  float w2v[4];
#pragma unroll
  for (int ni = 0; ni < 4; ++ni) w2v[ni] = W2[n0 + wc * 64 + ni * 16 + col];
#pragma unroll
  for (int mi = 0; mi < 4; ++mi) {
#pragma unroll
    for (int reg = 0; reg < 4; ++reg) {
      float v = 0.f;
#pragma unroll
      for (int ni = 0; ni < 4; ++ni) v += gelu_f(acc[mi][ni][reg]) * w2v[ni];
      v += __shfl_xor(v, 1);
      v += __shfl_xor(v, 2);
      v += __shfl_xor(v, 4);
      v += __shfl_xor(v, 8);
      if (col == 0)
        atomicAdd(diffz + m0 + wr * 64 + mi * 16 + quad * 4 + reg, v);
    }
  }
}

// ---------------- per-token finalize: one wave per token, 32 tokens/block ----------------
__global__ __launch_bounds__(256) void finalize_kernel(const float* __restrict__ logitsP,
                                                       const float* __restrict__ diffz,
                                                       float* __restrict__ out_idx,
                                                       float* __restrict__ out_scores,
                                                       float* __restrict__ out_probs,
                                                       float* __restrict__ imp_acc,
                                                       float* __restrict__ load_acc) {
  const int tid  = threadIdx.x;
  const int w    = tid >> 6, lane = tid & 63;
  const size_t PS = (size_t)BS_TOK * NEXP;
  float acc_imp = 0.f, acc_load = 0.f;
  for (int it = 0; it < 8; ++it) {
    const int t    = blockIdx.x * 32 + it * 4 + w;
    const float* lp = logitsP + (size_t)t * NEXP + lane;
    const float L  = ((lp[0] + lp[PS]) + lp[2 * PS]) + lp[3 * PS];
    const float z  = diffz[t];
    const float d  = 1.0f / (1.0f + expf(-z));
    const float l  = L / (1.0f + d);          // TEMP == 1
    // softmax
    float m = l;
#pragma unroll
    for (int off = 32; off > 0; off >>= 1) m = fmaxf(m, __shfl_xor(m, off));
    float p = expf(l - m);
    float s = p;
#pragma unroll
    for (int off = 32; off > 0; off >>= 1) s += __shfl_xor(s, off);
    p /= s;
    // top-1 (jax tie-break: lower index wins)
    float v = l; int bi = lane;
#pragma unroll
    for (int off = 32; off > 0; off >>= 1) {
      const float ov = __shfl_xor(v, off);
      const int   oi = __shfl_xor(bi, off);
      if (ov > v || (ov == v && oi < bi)) { v = ov; bi = oi; }
    }
    const int i1 = bi;
    // top-2
    float v2 = (lane == i1) ? -INFINITY : l;
    int bi2 = lane;
#pragma unroll
    for (int off = 32; off > 0; off >>= 1) {
      const float ov = __shfl_xor(v2, off);
      const int   oi = __shfl_xor(bi2, off);
      if (ov > v2 || (ov == v2 && oi < bi2)) { v2 = ov; bi2 = oi; }
    }
    const int i2 = bi2;
    const float p1 = __shfl(p, i1);
    const float p2 = __shfl(p, i2);
    const float s1 = (1.0f - p1) + p1;        // straight-through, fp32-faithful
    const float s2 = (1.0f - p2) + p2;
    const float den = fmaxf(s1 + s2, 1e-9f);
    if (lane == 0) {
      out_idx[t * 2]        = (float)i1;
      out_idx[t * 2 + 1]    = (float)i2;
      out_scores[t * 2]     = s1 / den;
      out_scores[t * 2 + 1] = s2 / den;
    }
    out_probs[(size_t)t * NEXP + lane] = p;
    acc_imp  += p;
    acc_load += (lane == i1 || lane == i2) ? 1.0f : 0.0f;
  }
  __shared__ float s_imp[256];
  __shared__ float s_hard[256];
  s_imp[tid]  = acc_imp;
  s_hard[tid] = acc_load;
  __syncthreads();
  if (tid < 64) {
    const float si = s_imp[tid] + s_imp[64 + tid] + s_imp[128 + tid] + s_imp[192 + tid];
    const float sl = s_hard[tid] + s_hard[64 + tid] + s_hard[128 + tid] + s_hard[192 + tid];
    atomicAdd(imp_acc + tid, si);
    atomicAdd(load_acc + tid, sl);
  }
}

// ---------------- importance/load scale ----------------
__global__ void scale_kernel(const float* __restrict__ acc,
                             float* __restrict__ out_imp,
                             float* __restrict__ out_load) {
  const int tid = threadIdx.x;
  const float inv = 1.0f / 16384.0f;
  if (tid < 64)       out_imp[tid]        = acc[tid] * inv;
  else if (tid < 128) out_load[tid - 64]  = acc[tid] * inv;
}

extern "C" void kernel_launch(void* const* d_in, const int* in_sizes, int n_in,
                              void* d_out, int out_size, void* d_ws, size_t ws_size,
                              hipStream_t stream) {
  (void)in_sizes; (void)n_in; (void)out_size; (void)ws_size;
  const float* X     = (const float*)d_in[0];
  const float* Wg    = (const float*)d_in[1];
  const float* gamma = (const float*)d_in[2];
  const float* beta  = (const float*)d_in[3];
  const float* W1    = (const float*)d_in[4];
  const float* W2    = (const float*)d_in[5];
  float* out = (float*)d_out;

  char* ws = (char*)d_ws;
  _Float16* H       = (_Float16*)(ws);                    // 64 MB
  _Float16* W1h     = (_Float16*)(ws + 67108864ull);      // 4 MB
  float*    logitsP = (float*)  (ws + 71303168ull);       // 16 MB (4 k-split partials)
  float*    diffz   = (float*)  (ws + 88080384ull);       // 64 KB
  float*    accs    = (float*)  (ws + 88145920ull);       // 512 B (imp[64], load[64])

  // out layout (all float32): idx[32768] | scores[32768] | probs[1048576] | imp[64] | load[64]
  float* out_idx    = out;
  float* out_scores = out + 32768;
  float* out_probs  = out + 65536;
  float* out_imp    = out + 1114112;
  float* out_load   = out + 1114176;

  hipMemsetAsync(diffz, 0, 65536ull + 512ull, stream);
  ln_kernel<<<BS_TOK / 4, 256, 0, stream>>>(X, gamma, beta, H);
  w1cast_kernel<<<(DHID * DIM) / (256 * 8), 256, 0, stream>>>(W1, W1h);
  gate_kernel<<<dim3(BS_TOK / 64, GKS), 256, 0, stream>>>(X, Wg, logitsP);
  g2_kernel<<<(DHID / 128) * (BS_TOK / 128), 256, 0, stream>>>(H, W1h, W2, diffz);
  finalize_kernel<<<BS_TOK / 32, 256, 0, stream>>>(logitsP, diffz, out_idx, out_scores,
                                                   out_probs, accs, accs + 64);
  scale_kernel<<<1, 128, 0, stream>>>(accs, out_imp, out_load);
}